// Round 5
// baseline (205.913 us; speedup 1.0000x reference)
//
#include <hip/hip_runtime.h>
#include <hip/hip_fp16.h>

// Problem constants: B=2, N=2048, T=8, M=256, D=1024, H=16, HD=64
// rows_x = B*N = 4096, rows_kv = B*T*M = 4096

typedef _Float16 h8 __attribute__((ext_vector_type(8)));
typedef _Float16 h4 __attribute__((ext_vector_type(4)));
typedef float f4 __attribute__((ext_vector_type(4)));

#define DI __device__ __forceinline__

DI void gload16(const void* g, void* l) {
  __builtin_amdgcn_global_load_lds((const __attribute__((address_space(1))) unsigned int*)g,
                                   (__attribute__((address_space(3))) unsigned int*)l, 16, 0, 0);
}

// raw barrier (no compiler-inserted vmcnt(0) drain) + compiler memory fence
#define BAR() do { asm volatile("" ::: "memory"); __builtin_amdgcn_s_barrier(); asm volatile("" ::: "memory"); } while (0)

// ---------------- fused prep: LN+cast | media cast | weight transpose | qlist ----------------
__global__ __launch_bounds__(256) void prep_kernel(
    const float* __restrict__ x, const float* __restrict__ gamma, const float* __restrict__ beta,
    _Float16* __restrict__ xh,
    const float* __restrict__ media, _Float16* __restrict__ kvh,
    const float* __restrict__ W0, const float* __restrict__ W1,
    const float* __restrict__ W2, const float* __restrict__ W3, _Float16* __restrict__ Wt,
    const int* __restrict__ locs, int* __restrict__ cnt, int* __restrict__ qlist) {
  int bid = blockIdx.x;
  int tid = threadIdx.x;
  if (bid < 4096) {
    int row = bid;
    const f4* xr = (const f4*)(x + (size_t)row * 1024);
    f4 v = xr[tid];
    float s = v[0] + v[1] + v[2] + v[3];
    float ss = v[0]*v[0] + v[1]*v[1] + v[2]*v[2] + v[3]*v[3];
    #pragma unroll
    for (int m = 1; m < 64; m <<= 1) { s += __shfl_xor(s, m); ss += __shfl_xor(ss, m); }
    __shared__ float red[8];
    int wid = tid >> 6, lane = tid & 63;
    if (lane == 0) { red[wid] = s; red[4 + wid] = ss; }
    __syncthreads();
    s = red[0] + red[1] + red[2] + red[3];
    ss = red[4] + red[5] + red[6] + red[7];
    float mean = s * (1.0f / 1024.0f);
    float var = ss * (1.0f / 1024.0f) - mean * mean;
    float rs = rsqrtf(var + 1e-5f);
    f4 g = ((const f4*)gamma)[tid], be = ((const f4*)beta)[tid];
    h4 o;
    #pragma unroll
    for (int j = 0; j < 4; ++j) o[j] = (_Float16)((v[j] - mean) * rs * g[j] + be[j]);
    ((h4*)(xh + (size_t)row * 1024))[tid] = o;
  } else if (bid < 8192) {
    int i = (bid - 4096) * 256 + tid;
    f4 v = ((const f4*)media)[i];
    h4 o;
    #pragma unroll
    for (int j = 0; j < 4; ++j) o[j] = (_Float16)v[j];
    ((h4*)kvh)[i] = o;
  } else if (bid < 12288) {
    int sec = bid - 8192;
    int z = sec >> 10, r = sec & 1023;
    const float* W = z == 0 ? W0 : z == 1 ? W1 : z == 2 ? W2 : W3;
    _Float16* out = Wt + (size_t)z * 1024 * 1024;
    __shared__ float tile[32][33];
    int i0 = (r & 31) * 32, o0 = (r >> 5) * 32;
    int tx = tid & 31, ty = tid >> 5;
    #pragma unroll
    for (int rr = 0; rr < 4; ++rr)
      tile[ty + rr * 8][tx] = W[(size_t)(i0 + ty + rr * 8) * 1024 + o0 + tx];
    __syncthreads();
    #pragma unroll
    for (int rr = 0; rr < 4; ++rr)
      out[(size_t)(o0 + ty + rr * 8) * 1024 + i0 + tx] = (_Float16)tile[tx][ty + rr * 8];
  } else {
    int b = bid - 12288;
    __shared__ int lcnt[8];
    if (tid < 8) lcnt[tid] = 0;
    __syncthreads();
    if (tid < 64) {
      int lane = tid;
      int run = 0; int v[32];
      #pragma unroll
      for (int i = 0; i < 32; ++i) { run += locs[b * 2048 + lane * 32 + i]; v[i] = run; }
      int incl = run;
      #pragma unroll
      for (int d = 1; d < 64; d <<= 1) { int t = __shfl_up(incl, d); if (lane >= d) incl += t; }
      int excl = incl - run;
      #pragma unroll
      for (int i = 0; i < 32; ++i) {
        int c = excl + v[i];
        if (c >= 1 && c <= 8) {
          int pos = atomicAdd(&lcnt[c - 1], 1);
          qlist[(b * 8 + (c - 1)) * 2048 + pos] = lane * 32 + i;
        }
      }
    }
    __syncthreads();
    if (tid < 8) cnt[b * 8 + tid] = lcnt[tid];
  }
}

struct GemmDesc { const _Float16* A; const _Float16* Bt; const float* bias; void* C; int mode; };
struct GemmBatch { GemmDesc d[3]; };

// ---------------- 256x256 MFMA GEMM, BK=64, 4-phase fine interleave (T3+T4+T5) ----------------
// 8 waves (2M x 4N), per-wave 128x64 = 8x4 frags of 16x16. LDS 128KB double-buffered.
// Phase = {stage 2 gloads of t+1 | 4-8 ds_read_b128 | bar | 16 MFMA (setprio) | bar}.
// One counted vmcnt(0)+bar per tile boundary (only next tile's 8 loads outstanding).
__global__ __launch_bounds__(512, 2) void gemm256(GemmBatch gb) {
  GemmDesc g = gb.d[blockIdx.z];
  int row0 = blockIdx.y * 256, col0 = blockIdx.x * 256;
  __shared__ alignas(16) _Float16 As[2][256 * 64];
  __shared__ alignas(16) _Float16 Bs[2][256 * 64];
  int tid = threadIdx.x, lane = tid & 63, wid = tid >> 6;
  int wr = wid >> 2, wc = wid & 3;
  // staging: thread covers rows rs + s*64, chunk (tid&7); source chunk pre-swizzled (rule 21)
  int rs = tid >> 3;
  int cg = (tid & 7) ^ (rs & 7);
  const _Float16* gA = g.A + (size_t)(row0 + rs) * 1024 + cg * 8;
  const _Float16* gB = g.Bt + (size_t)(col0 + rs) * 1024 + cg * 8;
  f4 acc[8][4] = {};

  // group 0: A rows 0-127; 1: A rows 128-255; 2: B rows 0-127; 3: B rows 128-255
  auto STAGEG = [&](int kt, int buf, int grp) {
    int s0 = (grp & 1) * 2;
    if (grp < 2) {
      gload16(gA + (size_t)s0 * 65536 + kt * 64,       (void*)&As[buf][s0 * 4096 + wid * 512]);
      gload16(gA + (size_t)(s0 + 1) * 65536 + kt * 64, (void*)&As[buf][(s0 + 1) * 4096 + wid * 512]);
    } else {
      gload16(gB + (size_t)s0 * 65536 + kt * 64,       (void*)&Bs[buf][s0 * 4096 + wid * 512]);
      gload16(gB + (size_t)(s0 + 1) * 65536 + kt * 64, (void*)&Bs[buf][(s0 + 1) * 4096 + wid * 512]);
    }
  };

  #pragma unroll
  for (int grp = 0; grp < 4; ++grp) STAGEG(0, 0, grp);
  asm volatile("s_waitcnt vmcnt(0)" ::: "memory");
  BAR();

  h8 bfr[4];
  #pragma unroll 1
  for (int t = 0; t < 16; ++t) {
    int buf = t & 1;
    #pragma unroll
    for (int ph = 0; ph < 4; ++ph) {
      int kk = ph >> 1, mh = ph & 1;
      if (t < 15) STAGEG(t + 1, buf ^ 1, ph);
      // ds reads for this phase (proven 0-conflict 16-row pattern)
      if (mh == 0) {
        #pragma unroll
        for (int n = 0; n < 4; ++n) {
          int r = wc * 64 + n * 16 + (lane & 15);
          int c = ((lane >> 4) + kk * 4) ^ (r & 7);
          bfr[n] = *(const h8*)&Bs[buf][r * 64 + c * 8];
        }
      }
      h8 afr[4];
      #pragma unroll
      for (int m = 0; m < 4; ++m) {
        int r = wr * 128 + mh * 64 + m * 16 + (lane & 15);
        int c = ((lane >> 4) + kk * 4) ^ (r & 7);
        afr[m] = *(const h8*)&As[buf][r * 64 + c * 8];
      }
      BAR();
      __builtin_amdgcn_s_setprio(1);
      #pragma unroll
      for (int m = 0; m < 4; ++m)
        #pragma unroll
        for (int n = 0; n < 4; ++n)
          acc[mh * 4 + m][n] = __builtin_amdgcn_mfma_f32_16x16x32_f16(afr[m], bfr[n], acc[mh * 4 + m][n], 0, 0, 0);
      __builtin_amdgcn_s_setprio(0);
      BAR();
    }
    if (t < 15) {
      asm volatile("s_waitcnt vmcnt(0)" ::: "memory");  // next tile's 8 loads landed (per wave)
      BAR();                                            // ... for ALL waves
    }
  }

  int colb = col0 + wc * 64;
  float bias_v[4];
  #pragma unroll
  for (int n = 0; n < 4; ++n) bias_v[n] = g.bias[colb + n * 16 + (lane & 15)];
  #pragma unroll
  for (int mi = 0; mi < 8; ++mi) {
    int row = row0 + wr * 128 + (mi >> 2) * 64 + (mi & 3) * 16 + (lane >> 4) * 4;
    #pragma unroll
    for (int n = 0; n < 4; ++n) {
      int col = colb + n * 16 + (lane & 15);
      if (g.mode == 0) {
        _Float16* C = (_Float16*)g.C;
        #pragma unroll
        for (int j = 0; j < 4; ++j)
          C[(size_t)(row + j) * 1024 + col] = (_Float16)(acc[mi][n][j] + bias_v[n]);
      } else if (g.mode == 1) {
        float* C = (float*)g.C;
        #pragma unroll
        for (int j = 0; j < 4; ++j)
          C[(size_t)(row + j) * 1024 + col] = acc[mi][n][j] + bias_v[n];
      } else {
        _Float16* C = (_Float16*)g.C;
        h4 pk;
        #pragma unroll
        for (int j = 0; j < 4; ++j) pk[j] = (_Float16)(acc[mi][n][j] + bias_v[n]);
        size_t vrow = (size_t)((row >> 11) * 1024 + col);   // (b*16+h)*64+d == b*1024+col
        *(h4*)&C[vrow * 2048 + (row & 2047)] = pk;
      }
    }
  }
}

// ---------------- 128x128 2-barrier GEMM (kept for out-projection: 256 blocks) ----------------
__global__ __launch_bounds__(512) void gemm128(GemmBatch gb) {
  GemmDesc g = gb.d[blockIdx.z];
  int row0 = blockIdx.y * 128, col0 = blockIdx.x * 128;
  __shared__ alignas(16) _Float16 As[128 * 64];
  __shared__ alignas(16) _Float16 Bs[128 * 64];
  int tid = threadIdx.x, lane = tid & 63, wid = tid >> 6;
  int wr = wid >> 2, wc = wid & 3;
  f4 acc[4][2] = {};
  int r0s = tid >> 3, c0s = tid & 7;
  int cg0 = c0s ^ (r0s & 7);
  int r1s = r0s + 64;
  int cg1 = c0s ^ (r1s & 7);
  const _Float16* gA0 = g.A + (size_t)(row0 + r0s) * 1024 + cg0 * 8;
  const _Float16* gA1 = g.A + (size_t)(row0 + r1s) * 1024 + cg1 * 8;
  const _Float16* gB0 = g.Bt + (size_t)(col0 + r0s) * 1024 + cg0 * 8;
  const _Float16* gB1 = g.Bt + (size_t)(col0 + r1s) * 1024 + cg1 * 8;
  #pragma unroll 1
  for (int kt = 0; kt < 16; ++kt) {
    __syncthreads();
    gload16(gA0 + kt * 64, (void*)&As[wid * 512]);
    gload16(gA1 + kt * 64, (void*)&As[4096 + wid * 512]);
    gload16(gB0 + kt * 64, (void*)&Bs[wid * 512]);
    gload16(gB1 + kt * 64, (void*)&Bs[4096 + wid * 512]);
    __syncthreads();
    h8 af[2][4], bf[2][2];
    #pragma unroll
    for (int kk = 0; kk < 2; ++kk) {
      #pragma unroll
      for (int m = 0; m < 4; ++m) {
        int r = wr * 64 + m * 16 + (lane & 15);
        int c = ((lane >> 4) + kk * 4) ^ (r & 7);
        af[kk][m] = *(const h8*)&As[r * 64 + c * 8];
      }
      #pragma unroll
      for (int n = 0; n < 2; ++n) {
        int r = wc * 32 + n * 16 + (lane & 15);
        int c = ((lane >> 4) + kk * 4) ^ (r & 7);
        bf[kk][n] = *(const h8*)&Bs[r * 64 + c * 8];
      }
    }
    #pragma unroll
    for (int kk = 0; kk < 2; ++kk)
      #pragma unroll
      for (int m = 0; m < 4; ++m)
        #pragma unroll
        for (int n = 0; n < 2; ++n)
          acc[m][n] = __builtin_amdgcn_mfma_f32_16x16x32_f16(af[kk][m], bf[kk][n], acc[m][n], 0, 0, 0);
  }
  int colb = col0 + wc * 32;
  float bias_v[2];
  #pragma unroll
  for (int n = 0; n < 2; ++n) bias_v[n] = g.bias[colb + n * 16 + (lane & 15)];
  #pragma unroll
  for (int m = 0; m < 4; ++m) {
    int row = row0 + wr * 64 + m * 16 + (lane >> 4) * 4;
    #pragma unroll
    for (int n = 0; n < 2; ++n) {
      int col = colb + n * 16 + (lane & 15);
      if (g.mode == 0) {
        _Float16* C = (_Float16*)g.C;
        #pragma unroll
        for (int j = 0; j < 4; ++j)
          C[(size_t)(row + j) * 1024 + col] = (_Float16)(acc[m][n][j] + bias_v[n]);
      } else if (g.mode == 1) {
        float* C = (float*)g.C;
        #pragma unroll
        for (int j = 0; j < 4; ++j)
          C[(size_t)(row + j) * 1024 + col] = acc[m][n][j] + bias_v[n];
      } else {
        _Float16* C = (_Float16*)g.C;
        h4 pk;
        #pragma unroll
        for (int j = 0; j < 4; ++j) pk[j] = (_Float16)(acc[m][n][j] + bias_v[n]);
        size_t vrow = (size_t)((row >> 11) * 1024 + col);
        *(h4*)&C[vrow * 2048 + (row & 2047)] = pk;
      }
    }
  }
}

// ---------------- masked cross-attention ----------------
__global__ __launch_bounds__(512) void attn_kernel(const _Float16* __restrict__ Qg,
    const _Float16* __restrict__ Kg, const _Float16* __restrict__ Vtg,
    const int* __restrict__ cnt, const int* __restrict__ qlist, _Float16* __restrict__ Og) {
  int h = blockIdx.x, f = blockIdx.y, b = blockIdx.z;
  __shared__ alignas(16) _Float16 Kl[256 * 64];
  __shared__ alignas(16) _Float16 Vl[64 * 256];
  __shared__ alignas(16) _Float16 Sl[8 * 16 * 256];
  int tid = threadIdx.x;
  for (int idx = tid; idx < 2048; idx += 512) {
    int r = idx >> 3, c = idx & 7;
    h8 v = *(const h8*)&Kg[((size_t)(b * 2048 + f * 256 + r)) * 1024 + h * 64 + c * 8];
    *(h8*)&Kl[r * 64 + ((c ^ (r & 7)) * 8)] = v;
  }
  for (int idx = tid; idx < 2048; idx += 512) {
    int d = idx >> 5, cc = idx & 31;
    h8 v = *(const h8*)&Vtg[((size_t)(b * 1024 + h * 64 + d)) * 2048 + f * 256 + cc * 8];
    *(h8*)&Vl[d * 256 + ((cc ^ (d & 7)) * 8)] = v;
  }
  __syncthreads();
  int nq = cnt[b * 8 + f];
  int lane = tid & 63, wid = tid >> 6;
  const int* ql = qlist + (b * 8 + f) * 2048;
  _Float16* Sw = &Sl[wid * 4096];
  for (int st = wid; st * 16 < nq; st += 8) {
    int qbase = st * 16;
    int nv = nq - qbase; if (nv > 16) nv = 16;
    int li = lane & 15; if (li > nv - 1) li = nv - 1;
    int qrow = b * 2048 + ql[qbase + li];
    h8 aq0 = *(const h8*)&Qg[(size_t)qrow * 1024 + h * 64 + (lane >> 4) * 8];
    h8 aq1 = *(const h8*)&Qg[(size_t)qrow * 1024 + h * 64 + 32 + (lane >> 4) * 8];
    f4 s[16];
    #pragma unroll
    for (int kt = 0; kt < 16; ++kt) {
      int key = kt * 16 + (lane & 15);
      int cb0 = lane >> 4;
      h8 bk0 = *(const h8*)&Kl[key * 64 + ((cb0 ^ (key & 7)) * 8)];
      h8 bk1 = *(const h8*)&Kl[key * 64 + (((cb0 + 4) ^ (key & 7)) * 8)];
      f4 z = {0.f, 0.f, 0.f, 0.f};
      s[kt] = __builtin_amdgcn_mfma_f32_16x16x32_f16(aq0, bk0, z, 0, 0, 0);
      s[kt] = __builtin_amdgcn_mfma_f32_16x16x32_f16(aq1, bk1, s[kt], 0, 0, 0);
    }
    float mx[4], sm[4];
    #pragma unroll
    for (int j = 0; j < 4; ++j) {
      float m = s[0][j];
      #pragma unroll
      for (int kt = 1; kt < 16; ++kt) m = fmaxf(m, s[kt][j]);
      #pragma unroll
      for (int d = 1; d < 16; d <<= 1) m = fmaxf(m, __shfl_xor(m, d));
      mx[j] = m; sm[j] = 0.f;
    }
    #pragma unroll
    for (int kt = 0; kt < 16; ++kt) {
      int keyb = kt * 16 + (lane & 15);
      int cbk = keyb >> 3, wi = keyb & 7;
      #pragma unroll
      for (int j = 0; j < 4; ++j) {
        float p = __expf((s[kt][j] - mx[j]) * 0.125f);
        sm[j] += p;
        int q = (lane >> 4) * 4 + j;
        Sw[q * 256 + ((cbk ^ (q & 7)) * 8) + wi] = (_Float16)p;
      }
    }
    #pragma unroll
    for (int j = 0; j < 4; ++j) {
      float x = sm[j];
      #pragma unroll
      for (int d = 1; d < 16; d <<= 1) x += __shfl_xor(x, d);
      sm[j] = x;
    }
    f4 o[4] = {};
    #pragma unroll
    for (int c32 = 0; c32 < 8; ++c32) {
      int qa = lane & 15;
      int cba = c32 * 4 + (lane >> 4);
      h8 pa = *(const h8*)&Sw[qa * 256 + ((cba ^ (qa & 7)) * 8)];
      #pragma unroll
      for (int dt = 0; dt < 4; ++dt) {
        int dd = dt * 16 + (lane & 15);
        h8 bv_ = *(const h8*)&Vl[dd * 256 + ((cba ^ (dd & 7)) * 8)];
        o[dt] = __builtin_amdgcn_mfma_f32_16x16x32_f16(pa, bv_, o[dt], 0, 0, 0);
      }
    }
    #pragma unroll
    for (int j = 0; j < 4; ++j) {
      int q = (lane >> 4) * 4 + j;
      if (q < nv) {
        int qr = __shfl(qrow, q);
        float inv = 1.0f / sm[j];
        #pragma unroll
        for (int dt = 0; dt < 4; ++dt)
          Og[(size_t)qr * 1024 + h * 64 + dt * 16 + (lane & 15)] = (_Float16)(o[dt][j] * inv);
      }
    }
  }
}

// ---------------- launch ----------------
extern "C" void kernel_launch(void* const* d_in, const int* in_sizes, int n_in,
                              void* d_out, int out_size, void* d_ws, size_t ws_size,
                              hipStream_t stream) {
  const float* text  = (const float*)d_in[0];
  const float* media = (const float*)d_in[1];
  const int*   locs  = (const int*)d_in[2];
  const float* gamma = (const float*)d_in[3];
  const float* beta  = (const float*)d_in[4];
  const float* wq = (const float*)d_in[5];
  const float* wk = (const float*)d_in[6];
  const float* wv = (const float*)d_in[7];
  const float* bq = (const float*)d_in[8];
  const float* bk = (const float*)d_in[9];
  const float* bv = (const float*)d_in[10];
  const float* wo = (const float*)d_in[11];
  const float* bo = (const float*)d_in[12];

  char* ws = (char*)d_ws;
  size_t off = 0;
  auto take = [&](size_t bytes) { void* p = ws + off; off += (bytes + 255) & ~(size_t)255; return p; };
  _Float16* xh  = (_Float16*)take((size_t)4096 * 1024 * 2);
  _Float16* kvh = (_Float16*)take((size_t)4096 * 1024 * 2);
  _Float16* wt  = (_Float16*)take((size_t)4 * 1024 * 1024 * 2);
  _Float16* Qm  = (_Float16*)take((size_t)4096 * 1024 * 2);
  _Float16* Km  = (_Float16*)take((size_t)4096 * 1024 * 2);
  _Float16* Vt  = (_Float16*)take((size_t)2048 * 2048 * 2);
  _Float16* Om  = (_Float16*)take((size_t)4096 * 1024 * 2);
  int* cnt   = (int*)take(64 * sizeof(int));
  int* qlist = (int*)take((size_t)2 * 8 * 2048 * sizeof(int));

  prep_kernel<<<12290, 256, 0, stream>>>(text, gamma, beta, xh, media, kvh,
                                         wq, wk, wv, wo, wt, locs, cnt, qlist);

  GemmBatch gb;
  gb.d[0] = { xh,  wt,                       bq, (void*)Qm, 0 };
  gb.d[1] = { kvh, wt + (size_t)1 * 1048576, bk, (void*)Km, 0 };
  gb.d[2] = { kvh, wt + (size_t)2 * 1048576, bv, (void*)Vt, 2 };
  gemm256<<<dim3(4, 16, 3), 512, 0, stream>>>(gb);

  attn_kernel<<<dim3(16, 8, 2), 512, 0, stream>>>(Qm, Km, Vt, cnt, qlist, Om);

  GemmBatch gf;
  gf.d[0] = { Om, wt + (size_t)3 * 1048576, bo, d_out, 1 };
  gf.d[1] = gf.d[0];
  gf.d[2] = gf.d[0];
  gemm128<<<dim3(8, 32, 1), 512, 0, stream>>>(gf);
}

// Round 6
// 173.148 us; speedup vs baseline: 1.1892x; 1.1892x over previous
//
#include <hip/hip_runtime.h>
#include <hip/hip_fp16.h>

// Problem constants: B=2, N=2048, T=8, M=256, D=1024, H=16, HD=64
// rows_x = B*N = 4096, rows_kv = B*T*M = 4096

typedef _Float16 h8 __attribute__((ext_vector_type(8)));
typedef _Float16 h4 __attribute__((ext_vector_type(4)));
typedef float f4 __attribute__((ext_vector_type(4)));

#define DI __device__ __forceinline__

DI void gload16(const void* g, void* l) {
  __builtin_amdgcn_global_load_lds((const __attribute__((address_space(1))) unsigned int*)g,
                                   (__attribute__((address_space(3))) unsigned int*)l, 16, 0, 0);
}

// ---------------- fused prep: LN+cast | media cast | weight transpose | qlist ----------------
// grid: [0,4096) ln rows; [4096,8192) media cast; [8192,9216) transpose (4 x 256 tiles); 9216..9217 qlist
__global__ __launch_bounds__(256) void prep_kernel(
    const float* __restrict__ x, const float* __restrict__ gamma, const float* __restrict__ beta,
    _Float16* __restrict__ xh,
    const float* __restrict__ media, _Float16* __restrict__ kvh,
    const float* __restrict__ W0, const float* __restrict__ W1,
    const float* __restrict__ W2, const float* __restrict__ W3, _Float16* __restrict__ Wt,
    const int* __restrict__ locs, int* __restrict__ cnt, int* __restrict__ qlist) {
  int bid = blockIdx.x;
  int tid = threadIdx.x;
  if (bid < 4096) {
    int row = bid;
    const f4* xr = (const f4*)(x + (size_t)row * 1024);
    f4 v = xr[tid];
    float s = v[0] + v[1] + v[2] + v[3];
    float ss = v[0]*v[0] + v[1]*v[1] + v[2]*v[2] + v[3]*v[3];
    #pragma unroll
    for (int m = 1; m < 64; m <<= 1) { s += __shfl_xor(s, m); ss += __shfl_xor(ss, m); }
    __shared__ float red[8];
    int wid = tid >> 6, lane = tid & 63;
    if (lane == 0) { red[wid] = s; red[4 + wid] = ss; }
    __syncthreads();
    s = red[0] + red[1] + red[2] + red[3];
    ss = red[4] + red[5] + red[6] + red[7];
    float mean = s * (1.0f / 1024.0f);
    float var = ss * (1.0f / 1024.0f) - mean * mean;
    float rs = rsqrtf(var + 1e-5f);
    f4 g = ((const f4*)gamma)[tid], be = ((const f4*)beta)[tid];
    h4 o;
    #pragma unroll
    for (int j = 0; j < 4; ++j) o[j] = (_Float16)((v[j] - mean) * rs * g[j] + be[j]);
    ((h4*)(xh + (size_t)row * 1024))[tid] = o;
  } else if (bid < 8192) {
    int i = (bid - 4096) * 256 + tid;
    f4 v = ((const f4*)media)[i];
    h4 o;
    #pragma unroll
    for (int j = 0; j < 4; ++j) o[j] = (_Float16)v[j];
    ((h4*)kvh)[i] = o;
  } else if (bid < 9216) {
    // ---- weight transpose + cast, 64x64 tiles: Wt[o][i] = W[i][o] ----
    int sec = bid - 8192;
    int z = sec >> 8, r = sec & 255;
    const float* W = z == 0 ? W0 : z == 1 ? W1 : z == 2 ? W2 : W3;
    _Float16* out = Wt + (size_t)z * 1024 * 1024;
    __shared__ float tileF[64][65];
    int i0 = (r & 15) * 64, o0 = (r >> 4) * 64;
    // read: f4 per thread, 16 i-rows per pass
    #pragma unroll
    for (int p = 0; p < 4; ++p) {
      int ir = p * 16 + (tid >> 4);
      f4 v = *(const f4*)&W[(size_t)(i0 + ir) * 1024 + o0 + (tid & 15) * 4];
      #pragma unroll
      for (int j = 0; j < 4; ++j) tileF[ir][(tid & 15) * 4 + j] = v[j];
    }
    __syncthreads();
    // write: h8 per thread (8 i's, 1 o), 32 o-rows per pass
    #pragma unroll
    for (int p = 0; p < 2; ++p) {
      int orow = p * 32 + (tid >> 3);
      h8 v;
      #pragma unroll
      for (int j = 0; j < 8; ++j) v[j] = (_Float16)tileF[(tid & 7) * 8 + j][orow];
      *(h8*)&out[(size_t)(o0 + orow) * 1024 + i0 + (tid & 7) * 8] = v;
    }
  } else {
    int b = bid - 9216;
    __shared__ int lcnt[8];
    if (tid < 8) lcnt[tid] = 0;
    __syncthreads();
    if (tid < 64) {
      int lane = tid;
      int run = 0; int v[32];
      #pragma unroll
      for (int i = 0; i < 32; ++i) { run += locs[b * 2048 + lane * 32 + i]; v[i] = run; }
      int incl = run;
      #pragma unroll
      for (int d = 1; d < 64; d <<= 1) { int t = __shfl_up(incl, d); if (lane >= d) incl += t; }
      int excl = incl - run;
      #pragma unroll
      for (int i = 0; i < 32; ++i) {
        int c = excl + v[i];
        if (c >= 1 && c <= 8) {
          int pos = atomicAdd(&lcnt[c - 1], 1);
          qlist[(b * 8 + (c - 1)) * 2048 + pos] = lane * 32 + i;
        }
      }
    }
    __syncthreads();
    if (tid < 8) cnt[b * 8 + tid] = lcnt[tid];
  }
}

struct GemmDesc { const _Float16* A; const _Float16* Bt; const float* bias; void* C; int mode; };
struct GemmBatch { GemmDesc d[3]; };

// ---------------- fp16 MFMA GEMM, 128x128 tile, BK=64, 8 waves (proven round-2) ----------------
// mode 0: C fp16 [.][1024];  mode 2: V transposed-per-head store: Vt[(b*16+h)*64+d][s], ld=2048
__global__ __launch_bounds__(512) void gemm128(GemmBatch gb) {
  GemmDesc g = gb.d[blockIdx.z];
  // XCD-aware swizzle within z-slice (256 blocks, 8 XCDs, cpx=32)
  int id = blockIdx.y * 8 + blockIdx.x;
  int id2 = (id & 7) * 32 + (id >> 3);
  int row0 = (id2 >> 3) * 128, col0 = (id2 & 7) * 128;
  __shared__ alignas(16) _Float16 As[128 * 64];
  __shared__ alignas(16) _Float16 Bs[128 * 64];
  int tid = threadIdx.x, lane = tid & 63, wid = tid >> 6;
  int wr = wid >> 2, wc = wid & 3;
  f4 acc[4][2] = {};
  int r0s = tid >> 3, c0s = tid & 7;
  int cg0 = c0s ^ (r0s & 7);
  const _Float16* gA0 = g.A + (size_t)(row0 + r0s) * 1024 + cg0 * 8;
  const _Float16* gA1 = gA0 + (size_t)64 * 1024;
  const _Float16* gB0 = g.Bt + (size_t)(col0 + r0s) * 1024 + cg0 * 8;
  const _Float16* gB1 = gB0 + (size_t)64 * 1024;
  #pragma unroll 1
  for (int kt = 0; kt < 16; ++kt) {
    __syncthreads();
    gload16(gA0 + kt * 64, (void*)&As[wid * 512]);
    gload16(gA1 + kt * 64, (void*)&As[4096 + wid * 512]);
    gload16(gB0 + kt * 64, (void*)&Bs[wid * 512]);
    gload16(gB1 + kt * 64, (void*)&Bs[4096 + wid * 512]);
    __syncthreads();
    h8 af[2][4], bf[2][2];
    #pragma unroll
    for (int kk = 0; kk < 2; ++kk) {
      #pragma unroll
      for (int m = 0; m < 4; ++m) {
        int r = wr * 64 + m * 16 + (lane & 15);
        int c = ((lane >> 4) + kk * 4) ^ (r & 7);
        af[kk][m] = *(const h8*)&As[r * 64 + c * 8];
      }
      #pragma unroll
      for (int n = 0; n < 2; ++n) {
        int r = wc * 32 + n * 16 + (lane & 15);
        int c = ((lane >> 4) + kk * 4) ^ (r & 7);
        bf[kk][n] = *(const h8*)&Bs[r * 64 + c * 8];
      }
    }
    #pragma unroll
    for (int kk = 0; kk < 2; ++kk)
      #pragma unroll
      for (int m = 0; m < 4; ++m)
        #pragma unroll
        for (int n = 0; n < 2; ++n)
          acc[m][n] = __builtin_amdgcn_mfma_f32_16x16x32_f16(af[kk][m], bf[kk][n], acc[m][n], 0, 0, 0);
  }
  int colb = col0 + wc * 32;
  float bias_v[2];
  #pragma unroll
  for (int n = 0; n < 2; ++n) bias_v[n] = g.bias[colb + n * 16 + (lane & 15)];
  #pragma unroll
  for (int m = 0; m < 4; ++m) {
    int row = row0 + wr * 64 + m * 16 + (lane >> 4) * 4;
    #pragma unroll
    for (int n = 0; n < 2; ++n) {
      int col = colb + n * 16 + (lane & 15);
      if (g.mode == 0) {
        _Float16* C = (_Float16*)g.C;
        #pragma unroll
        for (int j = 0; j < 4; ++j)
          C[(size_t)(row + j) * 1024 + col] = (_Float16)(acc[m][n][j] + bias_v[n]);
      } else {
        _Float16* C = (_Float16*)g.C;
        h4 pk;
        #pragma unroll
        for (int j = 0; j < 4; ++j) pk[j] = (_Float16)(acc[m][n][j] + bias_v[n]);
        size_t vrow = (size_t)((row >> 11) * 1024 + col);   // (b*16+h)*64+d == b*1024+col
        *(h4*)&C[vrow * 2048 + (row & 2047)] = pk;
      }
    }
  }
}

// ---------------- out-projection GEMM: 64x128 tile, BK=64, 512 blocks (2/CU) ----------------
__global__ __launch_bounds__(512) void gemm_out(const _Float16* __restrict__ A,
    const _Float16* __restrict__ Bt, const float* __restrict__ bias, float* __restrict__ C) {
  // 512 blocks, XCD swizzle cpx=64
  int id = blockIdx.y * 8 + blockIdx.x;
  int id2 = (id & 7) * 64 + (id >> 3);
  int row0 = (id2 >> 3) * 64, col0 = (id2 & 7) * 128;
  __shared__ alignas(16) _Float16 As[64 * 64];
  __shared__ alignas(16) _Float16 Bs[128 * 64];
  int tid = threadIdx.x, lane = tid & 63, wid = tid >> 6;
  int wr = wid >> 2, wc = wid & 3;   // wave: 32 rows x 32 cols
  f4 acc[2][2] = {};
  int rs = tid >> 3, c0s = tid & 7;
  int cg = c0s ^ (rs & 7);
  const _Float16* gA  = A  + (size_t)(row0 + rs) * 1024 + cg * 8;
  const _Float16* gB0 = Bt + (size_t)(col0 + rs) * 1024 + cg * 8;
  const _Float16* gB1 = gB0 + (size_t)64 * 1024;
  #pragma unroll 1
  for (int kt = 0; kt < 16; ++kt) {
    __syncthreads();
    gload16(gA  + kt * 64, (void*)&As[wid * 512]);
    gload16(gB0 + kt * 64, (void*)&Bs[wid * 512]);
    gload16(gB1 + kt * 64, (void*)&Bs[4096 + wid * 512]);
    __syncthreads();
    #pragma unroll
    for (int kk = 0; kk < 2; ++kk) {
      h8 a[2], b[2];
      #pragma unroll
      for (int m = 0; m < 2; ++m) {
        int r = wr * 32 + m * 16 + (lane & 15);
        int c = ((lane >> 4) + kk * 4) ^ (r & 7);
        a[m] = *(const h8*)&As[r * 64 + c * 8];
      }
      #pragma unroll
      for (int n = 0; n < 2; ++n) {
        int r = wc * 32 + n * 16 + (lane & 15);
        int c = ((lane >> 4) + kk * 4) ^ (r & 7);
        b[n] = *(const h8*)&Bs[r * 64 + c * 8];
      }
      #pragma unroll
      for (int m = 0; m < 2; ++m)
        #pragma unroll
        for (int n = 0; n < 2; ++n)
          acc[m][n] = __builtin_amdgcn_mfma_f32_16x16x32_f16(a[m], b[n], acc[m][n], 0, 0, 0);
    }
  }
  int colb = col0 + wc * 32;
  float bias_v[2];
  #pragma unroll
  for (int n = 0; n < 2; ++n) bias_v[n] = bias[colb + n * 16 + (lane & 15)];
  #pragma unroll
  for (int m = 0; m < 2; ++m) {
    int row = row0 + wr * 32 + m * 16 + (lane >> 4) * 4;
    #pragma unroll
    for (int n = 0; n < 2; ++n) {
      int col = colb + n * 16 + (lane & 15);
      #pragma unroll
      for (int j = 0; j < 4; ++j)
        C[(size_t)(row + j) * 1024 + col] = acc[m][n][j] + bias_v[n];
    }
  }
}

// ---------------- masked cross-attention ----------------
__global__ __launch_bounds__(512) void attn_kernel(const _Float16* __restrict__ Qg,
    const _Float16* __restrict__ Kg, const _Float16* __restrict__ Vtg,
    const int* __restrict__ cnt, const int* __restrict__ qlist, _Float16* __restrict__ Og) {
  int h = blockIdx.x, f = blockIdx.y, b = blockIdx.z;
  __shared__ alignas(16) _Float16 Kl[256 * 64];
  __shared__ alignas(16) _Float16 Vl[64 * 256];
  __shared__ alignas(16) _Float16 Sl[8 * 16 * 256];
  int tid = threadIdx.x;
  for (int idx = tid; idx < 2048; idx += 512) {
    int r = idx >> 3, c = idx & 7;
    h8 v = *(const h8*)&Kg[((size_t)(b * 2048 + f * 256 + r)) * 1024 + h * 64 + c * 8];
    *(h8*)&Kl[r * 64 + ((c ^ (r & 7)) * 8)] = v;
  }
  for (int idx = tid; idx < 2048; idx += 512) {
    int d = idx >> 5, cc = idx & 31;
    h8 v = *(const h8*)&Vtg[((size_t)(b * 1024 + h * 64 + d)) * 2048 + f * 256 + cc * 8];
    *(h8*)&Vl[d * 256 + ((cc ^ (d & 7)) * 8)] = v;
  }
  __syncthreads();
  int nq = cnt[b * 8 + f];
  int lane = tid & 63, wid = tid >> 6;
  const int* ql = qlist + (b * 8 + f) * 2048;
  _Float16* Sw = &Sl[wid * 4096];
  for (int st = wid; st * 16 < nq; st += 8) {
    int qbase = st * 16;
    int nv = nq - qbase; if (nv > 16) nv = 16;
    int li = lane & 15; if (li > nv - 1) li = nv - 1;
    int qrow = b * 2048 + ql[qbase + li];
    h8 aq0 = *(const h8*)&Qg[(size_t)qrow * 1024 + h * 64 + (lane >> 4) * 8];
    h8 aq1 = *(const h8*)&Qg[(size_t)qrow * 1024 + h * 64 + 32 + (lane >> 4) * 8];
    f4 s[16];
    #pragma unroll
    for (int kt = 0; kt < 16; ++kt) {
      int key = kt * 16 + (lane & 15);
      int cb0 = lane >> 4;
      h8 bk0 = *(const h8*)&Kl[key * 64 + ((cb0 ^ (key & 7)) * 8)];
      h8 bk1 = *(const h8*)&Kl[key * 64 + (((cb0 + 4) ^ (key & 7)) * 8)];
      f4 z = {0.f, 0.f, 0.f, 0.f};
      s[kt] = __builtin_amdgcn_mfma_f32_16x16x32_f16(aq0, bk0, z, 0, 0, 0);
      s[kt] = __builtin_amdgcn_mfma_f32_16x16x32_f16(aq1, bk1, s[kt], 0, 0, 0);
    }
    float mx[4], sm[4];
    #pragma unroll
    for (int j = 0; j < 4; ++j) {
      float m = s[0][j];
      #pragma unroll
      for (int kt = 1; kt < 16; ++kt) m = fmaxf(m, s[kt][j]);
      #pragma unroll
      for (int d = 1; d < 16; d <<= 1) m = fmaxf(m, __shfl_xor(m, d));
      mx[j] = m; sm[j] = 0.f;
    }
    #pragma unroll
    for (int kt = 0; kt < 16; ++kt) {
      int keyb = kt * 16 + (lane & 15);
      int cbk = keyb >> 3, wi = keyb & 7;
      #pragma unroll
      for (int j = 0; j < 4; ++j) {
        float p = __expf((s[kt][j] - mx[j]) * 0.125f);
        sm[j] += p;
        int q = (lane >> 4) * 4 + j;
        Sw[q * 256 + ((cbk ^ (q & 7)) * 8) + wi] = (_Float16)p;
      }
    }
    #pragma unroll
    for (int j = 0; j < 4; ++j) {
      float x = sm[j];
      #pragma unroll
      for (int d = 1; d < 16; d <<= 1) x += __shfl_xor(x, d);
      sm[j] = x;
    }
    f4 o[4] = {};
    #pragma unroll
    for (int c32 = 0; c32 < 8; ++c32) {
      int qa = lane & 15;
      int cba = c32 * 4 + (lane >> 4);
      h8 pa = *(const h8*)&Sw[qa * 256 + ((cba ^ (qa & 7)) * 8)];
      #pragma unroll
      for (int dt = 0; dt < 4; ++dt) {
        int dd = dt * 16 + (lane & 15);
        h8 bv_ = *(const h8*)&Vl[dd * 256 + ((cba ^ (dd & 7)) * 8)];
        o[dt] = __builtin_amdgcn_mfma_f32_16x16x32_f16(pa, bv_, o[dt], 0, 0, 0);
      }
    }
    #pragma unroll
    for (int j = 0; j < 4; ++j) {
      int q = (lane >> 4) * 4 + j;
      if (q < nv) {
        int qr = __shfl(qrow, q);
        float inv = 1.0f / sm[j];
        #pragma unroll
        for (int dt = 0; dt < 4; ++dt)
          Og[(size_t)qr * 1024 + h * 64 + dt * 16 + (lane & 15)] = (_Float16)(o[dt][j] * inv);
      }
    }
  }
}

// ---------------- launch ----------------
extern "C" void kernel_launch(void* const* d_in, const int* in_sizes, int n_in,
                              void* d_out, int out_size, void* d_ws, size_t ws_size,
                              hipStream_t stream) {
  const float* text  = (const float*)d_in[0];
  const float* media = (const float*)d_in[1];
  const int*   locs  = (const int*)d_in[2];
  const float* gamma = (const float*)d_in[3];
  const float* beta  = (const float*)d_in[4];
  const float* wq = (const float*)d_in[5];
  const float* wk = (const float*)d_in[6];
  const float* wv = (const float*)d_in[7];
  const float* bq = (const float*)d_in[8];
  const float* bk = (const float*)d_in[9];
  const float* bv = (const float*)d_in[10];
  const float* wo = (const float*)d_in[11];
  const float* bo = (const float*)d_in[12];

  char* ws = (char*)d_ws;
  size_t off = 0;
  auto take = [&](size_t bytes) { void* p = ws + off; off += (bytes + 255) & ~(size_t)255; return p; };
  _Float16* xh  = (_Float16*)take((size_t)4096 * 1024 * 2);
  _Float16* kvh = (_Float16*)take((size_t)4096 * 1024 * 2);
  _Float16* wt  = (_Float16*)take((size_t)4 * 1024 * 1024 * 2);
  _Float16* Qm  = (_Float16*)take((size_t)4096 * 1024 * 2);
  _Float16* Km  = (_Float16*)take((size_t)4096 * 1024 * 2);
  _Float16* Vt  = (_Float16*)take((size_t)2048 * 2048 * 2);
  _Float16* Om  = (_Float16*)take((size_t)4096 * 1024 * 2);
  int* cnt   = (int*)take(64 * sizeof(int));
  int* qlist = (int*)take((size_t)2 * 8 * 2048 * sizeof(int));

  prep_kernel<<<9218, 256, 0, stream>>>(text, gamma, beta, xh, media, kvh,
                                        wq, wk, wv, wo, wt, locs, cnt, qlist);

  GemmBatch gb;
  gb.d[0] = { xh,  wt,                       bq, (void*)Qm, 0 };
  gb.d[1] = { kvh, wt + (size_t)1 * 1048576, bk, (void*)Km, 0 };
  gb.d[2] = { kvh, wt + (size_t)2 * 1048576, bv, (void*)Vt, 2 };
  gemm128<<<dim3(8, 32, 3), 512, 0, stream>>>(gb);

  attn_kernel<<<dim3(16, 8, 2), 512, 0, stream>>>(Qm, Km, Vt, cnt, qlist, Om);

  gemm_out<<<dim3(8, 64), 512, 0, stream>>>(Om, wt + (size_t)3 * 1048576, bo, (float*)d_out);
}